// Round 12
// baseline (105.621 us; speedup 1.0000x reference)
//
#include <hip/hip_runtime.h>

#define BATCH 32

typedef float f32x4 __attribute__((ext_vector_type(4)));

// ---------------------------------------------------------------------------
// Kernel 1: build the global output-row -> source-row table.
// srcg[b*max_len + j] = b*T + t for j in [cs[t-1], cs[t]);  -1 for padded tail.
// One block of T=1024 threads per batch. ~460 KB in d_ws.
// ---------------------------------------------------------------------------
__global__ void build_src_kernel(const int* __restrict__ dur,
                                 int* __restrict__ srcg,
                                 int T, int max_len) {
    const int b = blockIdx.x;
    const int tid = threadIdx.x;          // 0..T-1
    const int lane = tid & 63;
    const int w = tid >> 6;               // 0..15

    __shared__ int part[16];
    __shared__ int totsh;

    const int d = dur[b * T + tid];
    int v = d;
    #pragma unroll
    for (int off = 1; off < 64; off <<= 1) {
        int u = __shfl_up(v, off, 64);
        if (lane >= off) v += u;
    }
    if (lane == 63) part[w] = v;
    __syncthreads();
    if (w == 0 && lane < 16) {
        int p = part[lane];
        #pragma unroll
        for (int off = 1; off < 16; off <<= 1) {
            int u = __shfl_up(p, off, 16);
            if (lane >= off) p += u;
        }
        part[lane] = p;
    }
    __syncthreads();

    const int end = v + (w > 0 ? part[w - 1] : 0);  // inclusive cumsum at tid
    const int start = end - d;
    if (tid == T - 1) totsh = end;

    int* __restrict__ srow = srcg + (size_t)b * max_len;
    const int sval = b * T + tid;
    for (int j = start; j < end; ++j) srow[j] = sval;  // disjoint ranges
    __syncthreads();

    const int total = totsh;
    for (int i = total + tid; i < max_len; i += blockDim.x) srow[i] = -1;
}

// ---------------------------------------------------------------------------
// Kernel 2: swept gather-copy (R11 structure — the −9% win).
// A/B vs R11, ONE variable: stores are PLAIN (L2-routed) instead of NT.
// Rationale: the instantaneous write window of the swept front is
// 8192 rows x 3 KB = 24 MB < 32 MB aggregate L2 — plain stores let L2
// absorb/combine full lines and drain asynchronously (the regime where the
// harness fill sustains 6.9 TB/s). NT stores bypass exactly that.
// ---------------------------------------------------------------------------
__global__ __launch_bounds__(256, 8)
void expand_sweep_kernel(const float* __restrict__ x,
                         const int* __restrict__ srcg,
                         float* __restrict__ out,
                         int D, long R) {
    const int lane = threadIdx.x & 63;
    const long q = (long)((blockIdx.x * blockDim.x + threadIdx.x) >> 6);
    const long NW = (long)((gridDim.x * blockDim.x) >> 6);

    long r = q;
    if (r >= R) return;

    int s_cur = srcg[r];                  // wave-uniform
    long rn = r + NW;
    int s_nxt = (rn < R) ? srcg[rn] : -1;

    f32x4 a0 = (f32x4)(0.f), a1 = a0, a2 = a0;
    if (s_cur >= 0) {
        const f32x4* sp = reinterpret_cast<const f32x4*>(x + (size_t)s_cur * D);
        a0 = sp[lane]; a1 = sp[lane + 64]; a2 = sp[lane + 128];
    }

    while (true) {
        // issue next frame load early (1-step lookahead)
        f32x4 n0 = (f32x4)(0.f), n1 = n0, n2 = n0;
        if (rn < R && s_nxt >= 0) {
            const f32x4* sp = reinterpret_cast<const f32x4*>(x + (size_t)s_nxt * D);
            n0 = sp[lane]; n1 = sp[lane + 64]; n2 = sp[lane + 128];
        }
        // prefetch src two steps ahead
        const long rnn = rn + NW;
        const int s_nn = (rnn < R) ? srcg[rnn] : -1;

        // store current row — PLAIN stores (the A/B variable)
        f32x4* dst = reinterpret_cast<f32x4*>(out + (size_t)r * D);
        dst[lane]       = a0;
        dst[lane + 64]  = a1;
        dst[lane + 128] = a2;

        if (rn >= R) break;
        r = rn; rn = rnn;
        s_cur = s_nxt; s_nxt = s_nn;
        a0 = n0; a1 = n1; a2 = n2;
    }
}

extern "C" void kernel_launch(void* const* d_in, const int* in_sizes, int n_in,
                              void* d_out, int out_size, void* d_ws, size_t ws_size,
                              hipStream_t stream) {
    const float* x = (const float*)d_in[0];
    const int* dur = (const int*)d_in[1];
    float* out = (float*)d_out;

    const int BT = in_sizes[1];          // B*T
    const int B = BATCH;
    const int T = BT / B;                // 1024
    const int D = in_sizes[0] / BT;      // 768
    const int max_len = out_size / (B * D);

    int* srcg = (int*)d_ws;              // B*max_len ints (~460 KB)

    build_src_kernel<<<B, T, 0, stream>>>(dur, srcg, T, max_len);

    const long R = (long)B * max_len;
    expand_sweep_kernel<<<2048, 256, 0, stream>>>(x, srcg, out, D, R);
}

// Round 13
// 80.338 us; speedup vs baseline: 1.3147x; 1.3147x over previous
//
#include <hip/hip_runtime.h>

#define BATCH 32

typedef float f32x4 __attribute__((ext_vector_type(4)));

// ---------------------------------------------------------------------------
// Kernel 1: build the global output-row -> source-row table (unchanged R11).
// srcg[b*max_len + j] = b*T + t for j in [cs[t-1], cs[t]);  -1 for padded tail.
// ---------------------------------------------------------------------------
__global__ void build_src_kernel(const int* __restrict__ dur,
                                 int* __restrict__ srcg,
                                 int T, int max_len) {
    const int b = blockIdx.x;
    const int tid = threadIdx.x;          // 0..T-1
    const int lane = tid & 63;
    const int w = tid >> 6;               // 0..15

    __shared__ int part[16];
    __shared__ int totsh;

    const int d = dur[b * T + tid];
    int v = d;
    #pragma unroll
    for (int off = 1; off < 64; off <<= 1) {
        int u = __shfl_up(v, off, 64);
        if (lane >= off) v += u;
    }
    if (lane == 63) part[w] = v;
    __syncthreads();
    if (w == 0 && lane < 16) {
        int p = part[lane];
        #pragma unroll
        for (int off = 1; off < 16; off <<= 1) {
            int u = __shfl_up(p, off, 16);
            if (lane >= off) p += u;
        }
        part[lane] = p;
    }
    __syncthreads();

    const int end = v + (w > 0 ? part[w - 1] : 0);
    const int start = end - d;
    if (tid == T - 1) totsh = end;

    int* __restrict__ srow = srcg + (size_t)b * max_len;
    const int sval = b * T + tid;
    for (int j = start; j < end; ++j) srow[j] = sval;
    __syncthreads();

    const int total = totsh;
    for (int i = total + tid; i < max_len; i += blockDim.x) srow[i] = -1;
}

// ---------------------------------------------------------------------------
// Kernel 2: swept gather-copy, PAIR variant (vs R11 champion).
// Wave q handles row-pairs {2p, 2p+1}, p = q + k*NW. Adjacent rows share the
// source frame ~71% of the time -> payload register reuse instead of reload;
// each iteration emits a 6 KB contiguous NT-store burst (2x R11's MLP).
// Dependent chain fully pipelined as in R11: src pair prefetched 2 steps
// ahead, frames 1 step ahead. NT stores (R12 proved plain stores -23%).
// 48 payload VGPRs -> __launch_bounds__(256,6) (~85 VGPR cap, 24 waves/CU).
// ---------------------------------------------------------------------------
__global__ __launch_bounds__(256, 6)
void expand_sweep2_kernel(const float* __restrict__ x,
                          const int* __restrict__ srcg,
                          float* __restrict__ out,
                          int D, long P, long NW) {
    const int lane = threadIdx.x & 63;
    const long q = (long)((blockIdx.x * blockDim.x + threadIdx.x) >> 6);

    long p = q;
    if (p >= P) return;

    int s0 = srcg[2 * p];
    int s1 = srcg[2 * p + 1];
    long pn = p + NW;
    int t0 = (pn < P) ? srcg[2 * pn]     : -1;
    int t1 = (pn < P) ? srcg[2 * pn + 1] : -1;

    f32x4 a0 = (f32x4)(0.f), a1 = a0, a2 = a0, b0 = a0, b1 = a0, b2 = a0;
    if (s0 >= 0) {
        const f32x4* sp = reinterpret_cast<const f32x4*>(x + (size_t)s0 * D);
        a0 = sp[lane]; a1 = sp[lane + 64]; a2 = sp[lane + 128];
    }
    if (s1 == s0) { b0 = a0; b1 = a1; b2 = a2; }
    else if (s1 >= 0) {
        const f32x4* sp = reinterpret_cast<const f32x4*>(x + (size_t)s1 * D);
        b0 = sp[lane]; b1 = sp[lane + 64]; b2 = sp[lane + 128];
    }

    while (true) {
        // issue next-pair frame loads early (1-step lookahead, shared if same)
        f32x4 n0 = (f32x4)(0.f), n1 = n0, n2 = n0, m0 = n0, m1 = n0, m2 = n0;
        if (pn < P) {
            if (t0 >= 0) {
                const f32x4* sp = reinterpret_cast<const f32x4*>(x + (size_t)t0 * D);
                n0 = sp[lane]; n1 = sp[lane + 64]; n2 = sp[lane + 128];
            }
            if (t1 == t0) { m0 = n0; m1 = n1; m2 = n2; }
            else if (t1 >= 0) {
                const f32x4* sp = reinterpret_cast<const f32x4*>(x + (size_t)t1 * D);
                m0 = sp[lane]; m1 = sp[lane + 64]; m2 = sp[lane + 128];
            }
        }
        // prefetch src pair two steps ahead
        const long pnn = pn + NW;
        const int u0 = (pnn < P) ? srcg[2 * pnn]     : -1;
        const int u1 = (pnn < P) ? srcg[2 * pnn + 1] : -1;

        // store current pair: rows 2p,2p+1 contiguous -> 6 KB NT burst
        f32x4* dst = reinterpret_cast<f32x4*>(out + (size_t)(2 * p) * D);
        __builtin_nontemporal_store(a0, &dst[lane]);
        __builtin_nontemporal_store(a1, &dst[lane + 64]);
        __builtin_nontemporal_store(a2, &dst[lane + 128]);
        __builtin_nontemporal_store(b0, &dst[lane + 192]);
        __builtin_nontemporal_store(b1, &dst[lane + 256]);
        __builtin_nontemporal_store(b2, &dst[lane + 320]);

        if (pn >= P) break;
        p = pn; pn = pnn;
        s0 = t0; s1 = t1; t0 = u0; t1 = u1;
        a0 = n0; a1 = n1; a2 = n2; b0 = m0; b1 = m1; b2 = m2;
    }
}

extern "C" void kernel_launch(void* const* d_in, const int* in_sizes, int n_in,
                              void* d_out, int out_size, void* d_ws, size_t ws_size,
                              hipStream_t stream) {
    const float* x = (const float*)d_in[0];
    const int* dur = (const int*)d_in[1];
    float* out = (float*)d_out;

    const int BT = in_sizes[1];          // B*T
    const int B = BATCH;
    const int T = BT / B;                // 1024
    const int D = in_sizes[0] / BT;      // 768
    const int max_len = out_size / (B * D);

    int* srcg = (int*)d_ws;              // B*max_len ints (~460 KB)

    build_src_kernel<<<B, T, 0, stream>>>(dur, srcg, T, max_len);

    const long R = (long)B * max_len;    // even (B=32)
    const long P = R >> 1;               // row pairs
    const long NW = 2048L * 4;           // 8192 waves
    expand_sweep2_kernel<<<2048, 256, 0, stream>>>(x, srcg, out, D, P, NW);
}

// Round 14
// 78.396 us; speedup vs baseline: 1.3473x; 1.0248x over previous
//
#include <hip/hip_runtime.h>

#define BATCH 32

typedef float f32x4 __attribute__((ext_vector_type(4)));

// ---------------------------------------------------------------------------
// Kernel 1: build the global output-row -> source-row table (unchanged R11).
// srcg[b*max_len + j] = b*T + t for j in [cs[t-1], cs[t]);  -1 for padded tail.
// ---------------------------------------------------------------------------
__global__ void build_src_kernel(const int* __restrict__ dur,
                                 int* __restrict__ srcg,
                                 int T, int max_len) {
    const int b = blockIdx.x;
    const int tid = threadIdx.x;          // 0..T-1
    const int lane = tid & 63;
    const int w = tid >> 6;               // 0..15

    __shared__ int part[16];
    __shared__ int totsh;

    const int d = dur[b * T + tid];
    int v = d;
    #pragma unroll
    for (int off = 1; off < 64; off <<= 1) {
        int u = __shfl_up(v, off, 64);
        if (lane >= off) v += u;
    }
    if (lane == 63) part[w] = v;
    __syncthreads();
    if (w == 0 && lane < 16) {
        int p = part[lane];
        #pragma unroll
        for (int off = 1; off < 16; off <<= 1) {
            int u = __shfl_up(p, off, 16);
            if (lane >= off) p += u;
        }
        part[lane] = p;
    }
    __syncthreads();

    const int end = v + (w > 0 ? part[w - 1] : 0);
    const int start = end - d;
    if (tid == T - 1) totsh = end;

    int* __restrict__ srow = srcg + (size_t)b * max_len;
    const int sval = b * T + tid;
    for (int j = start; j < end; ++j) srow[j] = sval;
    __syncthreads();

    const int total = totsh;
    for (int i = total + tid; i < max_len; i += blockDim.x) srow[i] = -1;
}

// ---------------------------------------------------------------------------
// Kernel 2: swept gather-copy, QUAD variant (vs R13 pair champion).
// Wave q handles row-quads {4p..4p+3}. A quad spans ~2 distinct frames on
// average (dur~3.5) -> share-chain register copies replace ~half the frame
// loads; each iteration emits a 12 KB contiguous NT-store burst.
// Same pipeline as R13: src quad prefetched 2 steps ahead, frames 1 ahead.
// NT stores (R12: plain = -23%). Payload 2 x 48 VGPRs ->
// __launch_bounds__(256,4), 16 waves/CU (plenty for streaming; harness fill
// hits 6.9 TB/s at 11% occupancy). All payload indexing via fully-unrolled
// compile-time loops (rule #20).
// ---------------------------------------------------------------------------
__global__ __launch_bounds__(256, 4)
void expand_sweep4_kernel(const float* __restrict__ x,
                          const int* __restrict__ srcg,
                          float* __restrict__ out,
                          int D, long P, long NW) {
    const int lane = threadIdx.x & 63;
    const long q = (long)((blockIdx.x * blockDim.x + threadIdx.x) >> 6);

    long p = q;
    if (p >= P) return;

    int s[4], t[4];
    #pragma unroll
    for (int k = 0; k < 4; ++k) s[k] = srcg[4 * p + k];
    long pn = p + NW;
    #pragma unroll
    for (int k = 0; k < 4; ++k) t[k] = (pn < P) ? srcg[4 * pn + k] : -1;

    f32x4 cur[4][3], nxt[4][3];

    // load current quad payload with share-chain
    #pragma unroll
    for (int k = 0; k < 4; ++k) {
        if (k > 0 && s[k] == s[k - 1]) {
            #pragma unroll
            for (int j = 0; j < 3; ++j) cur[k][j] = cur[k - 1][j];
        } else if (s[k] >= 0) {
            const f32x4* sp = reinterpret_cast<const f32x4*>(x + (size_t)s[k] * D);
            cur[k][0] = sp[lane];
            cur[k][1] = sp[lane + 64];
            cur[k][2] = sp[lane + 128];
        } else {
            #pragma unroll
            for (int j = 0; j < 3; ++j) cur[k][j] = (f32x4)(0.f);
        }
    }

    while (true) {
        // 1-step-ahead frame loads for the next quad (share-chain)
        if (pn < P) {
            #pragma unroll
            for (int k = 0; k < 4; ++k) {
                if (k > 0 && t[k] == t[k - 1]) {
                    #pragma unroll
                    for (int j = 0; j < 3; ++j) nxt[k][j] = nxt[k - 1][j];
                } else if (t[k] >= 0) {
                    const f32x4* sp = reinterpret_cast<const f32x4*>(x + (size_t)t[k] * D);
                    nxt[k][0] = sp[lane];
                    nxt[k][1] = sp[lane + 64];
                    nxt[k][2] = sp[lane + 128];
                } else {
                    #pragma unroll
                    for (int j = 0; j < 3; ++j) nxt[k][j] = (f32x4)(0.f);
                }
            }
        }
        // src prefetch 2 steps ahead
        const long pnn = pn + NW;
        int u[4];
        #pragma unroll
        for (int k = 0; k < 4; ++k) u[k] = (pnn < P) ? srcg[4 * pnn + k] : -1;

        // 12 KB contiguous NT-store burst (rows 4p..4p+3)
        f32x4* dst = reinterpret_cast<f32x4*>(out + (size_t)(4 * p) * D);
        #pragma unroll
        for (int k = 0; k < 4; ++k) {
            __builtin_nontemporal_store(cur[k][0], &dst[lane + 192 * k]);
            __builtin_nontemporal_store(cur[k][1], &dst[lane + 192 * k + 64]);
            __builtin_nontemporal_store(cur[k][2], &dst[lane + 192 * k + 128]);
        }

        if (pn >= P) break;
        p = pn; pn = pnn;
        #pragma unroll
        for (int k = 0; k < 4; ++k) {
            s[k] = t[k]; t[k] = u[k];
            #pragma unroll
            for (int j = 0; j < 3; ++j) cur[k][j] = nxt[k][j];
        }
    }
}

extern "C" void kernel_launch(void* const* d_in, const int* in_sizes, int n_in,
                              void* d_out, int out_size, void* d_ws, size_t ws_size,
                              hipStream_t stream) {
    const float* x = (const float*)d_in[0];
    const int* dur = (const int*)d_in[1];
    float* out = (float*)d_out;

    const int BT = in_sizes[1];          // B*T
    const int B = BATCH;
    const int T = BT / B;                // 1024
    const int D = in_sizes[0] / BT;      // 768
    const int max_len = out_size / (B * D);

    int* srcg = (int*)d_ws;              // B*max_len ints (~460 KB)

    build_src_kernel<<<B, T, 0, stream>>>(dur, srcg, T, max_len);

    const long R = (long)B * max_len;    // divisible by 4 (B=32)
    const long P = R >> 2;               // row quads
    const long NW = 2048L * 4;           // 8192 waves
    expand_sweep4_kernel<<<2048, 256, 0, stream>>>(x, srcg, out, D, P, NW);
}

// Round 15
// 77.665 us; speedup vs baseline: 1.3599x; 1.0094x over previous
//
#include <hip/hip_runtime.h>

#define BATCH 32

typedef float f32x4 __attribute__((ext_vector_type(4)));

// ---------------------------------------------------------------------------
// Kernel 1: build the global output-row -> source-row table (unchanged R11).
// srcg[b*max_len + j] = b*T + t for j in [cs[t-1], cs[t]);  -1 for padded tail.
// ---------------------------------------------------------------------------
__global__ void build_src_kernel(const int* __restrict__ dur,
                                 int* __restrict__ srcg,
                                 int T, int max_len) {
    const int b = blockIdx.x;
    const int tid = threadIdx.x;          // 0..T-1
    const int lane = tid & 63;
    const int w = tid >> 6;               // 0..15

    __shared__ int part[16];
    __shared__ int totsh;

    const int d = dur[b * T + tid];
    int v = d;
    #pragma unroll
    for (int off = 1; off < 64; off <<= 1) {
        int u = __shfl_up(v, off, 64);
        if (lane >= off) v += u;
    }
    if (lane == 63) part[w] = v;
    __syncthreads();
    if (w == 0 && lane < 16) {
        int p = part[lane];
        #pragma unroll
        for (int off = 1; off < 16; off <<= 1) {
            int u = __shfl_up(p, off, 16);
            if (lane >= off) p += u;
        }
        part[lane] = p;
    }
    __syncthreads();

    const int end = v + (w > 0 ? part[w - 1] : 0);
    const int start = end - d;
    if (tid == T - 1) totsh = end;

    int* __restrict__ srow = srcg + (size_t)b * max_len;
    const int sval = b * T + tid;
    for (int j = start; j < end; ++j) srow[j] = sval;
    __syncthreads();

    const int total = totsh;
    for (int i = total + tid; i < max_len; i += blockDim.x) srow[i] = -1;
}

// ---------------------------------------------------------------------------
// Kernel 2: swept gather-copy, OCTET variant (vs R14 quad champion).
// Wave q handles 8 consecutive rows per iteration: 24 KB contiguous NT-store
// burst; share-chain collapses ~8 rows -> ~2.3 distinct frame loads.
// Frames single-buffered (96 payload VGPRs; double-buffer doesn't fit) —
// latency covered by TLP (12 waves/CU). srcg octet prefetched 2 steps ahead
// so the dependent address chain never sits in front of the stores.
// NT stores (R12: plain = -23%). All payload indexing fully unrolled.
// ---------------------------------------------------------------------------
__global__ __launch_bounds__(256, 3)
void expand_sweep8_kernel(const float* __restrict__ x,
                          const int* __restrict__ srcg,
                          float* __restrict__ out,
                          int D, long P, long NW) {
    const int lane = threadIdx.x & 63;
    const long q = (long)((blockIdx.x * blockDim.x + threadIdx.x) >> 6);

    long p = q;
    if (p >= P) return;

    int s[8], t[8];
    #pragma unroll
    for (int k = 0; k < 8; ++k) s[k] = srcg[8 * p + k];
    long pn = p + NW;
    #pragma unroll
    for (int k = 0; k < 8; ++k) t[k] = (pn < P) ? srcg[8 * pn + k] : -1;

    f32x4 cur[8][3];

    while (true) {
        // load this octet's payload (share-chain: copy regs when frame repeats)
        #pragma unroll
        for (int k = 0; k < 8; ++k) {
            if (k > 0 && s[k] == s[k - 1]) {
                #pragma unroll
                for (int j = 0; j < 3; ++j) cur[k][j] = cur[k - 1][j];
            } else if (s[k] >= 0) {
                const f32x4* sp = reinterpret_cast<const f32x4*>(x + (size_t)s[k] * D);
                cur[k][0] = sp[lane];
                cur[k][1] = sp[lane + 64];
                cur[k][2] = sp[lane + 128];
            } else {
                #pragma unroll
                for (int j = 0; j < 3; ++j) cur[k][j] = (f32x4)(0.f);
            }
        }

        // srcg prefetch 2 steps ahead (address chain stays off the stores)
        const long pnn = pn + NW;
        int u[8];
        #pragma unroll
        for (int k = 0; k < 8; ++k) u[k] = (pnn < P) ? srcg[8 * pnn + k] : -1;

        // 24 KB contiguous NT-store burst (rows 8p..8p+7)
        f32x4* dst = reinterpret_cast<f32x4*>(out + (size_t)(8 * p) * D);
        #pragma unroll
        for (int k = 0; k < 8; ++k) {
            __builtin_nontemporal_store(cur[k][0], &dst[lane + 192 * k]);
            __builtin_nontemporal_store(cur[k][1], &dst[lane + 192 * k + 64]);
            __builtin_nontemporal_store(cur[k][2], &dst[lane + 192 * k + 128]);
        }

        if (pn >= P) break;
        p = pn; pn = pnn;
        #pragma unroll
        for (int k = 0; k < 8; ++k) { s[k] = t[k]; t[k] = u[k]; }
    }
}

extern "C" void kernel_launch(void* const* d_in, const int* in_sizes, int n_in,
                              void* d_out, int out_size, void* d_ws, size_t ws_size,
                              hipStream_t stream) {
    const float* x = (const float*)d_in[0];
    const int* dur = (const int*)d_in[1];
    float* out = (float*)d_out;

    const int BT = in_sizes[1];          // B*T
    const int B = BATCH;
    const int T = BT / B;                // 1024
    const int D = in_sizes[0] / BT;      // 768
    const int max_len = out_size / (B * D);

    int* srcg = (int*)d_ws;              // B*max_len ints (~460 KB)

    build_src_kernel<<<B, T, 0, stream>>>(dur, srcg, T, max_len);

    const long R = (long)B * max_len;    // divisible by 32 (B=32)
    const long P = R >> 3;               // row octets
    const long NW = 2048L * 4;           // 8192 waves
    expand_sweep8_kernel<<<2048, 256, 0, stream>>>(x, srcg, out, D, P, NW);
}